// Round 10
// baseline (417.181 us; speedup 1.0000x reference)
//
#include <hip/hip_runtime.h>
#include <stdint.h>

#define BN_EPS 1e-5f
#define BW    256        // nodes per bucket
#define BSH   8          // log2(BW)
#define SLACK 10240      // entries reserved per bucket (mean ~8184, huge margin)
#define TILE  4096       // edges per binning block

static __device__ __forceinline__ uint32_t bf16bits(float f){
  uint32_t u = __float_as_uint(f);
  return (u + 0x7fffu + ((u>>16)&1u)) >> 16;
}
static __device__ __forceinline__ float bf16tof(uint32_t us){
  return __uint_as_float(us<<16);
}

// ---------- weight precompute + breakpoint sort ----------
__global__ __launch_bounds__(256) void prep_small(const float* __restrict__ w1a, const float* __restrict__ b1a,
                           const float* __restrict__ g1,  const float* __restrict__ be1,
                           const float* __restrict__ m1,  const float* __restrict__ v1,
                           const float* __restrict__ b1b, const float* __restrict__ w2a,
                           const float* __restrict__ b2a, const float* __restrict__ g2,
                           const float* __restrict__ be2, const float* __restrict__ m2,
                           const float* __restrict__ v2,
                           float* __restrict__ a1, float* __restrict__ b1v,
                           float* __restrict__ c12, float* __restrict__ A2, float* __restrict__ B2,
                           float* __restrict__ sorted_p, int* __restrict__ perm){
  __shared__ float bpl[256];
  int c = threadIdx.x;
  float s1 = g1[c] * rsqrtf(v1[c] + BN_EPS);
  float av = w1a[c] * s1;
  float bv = (b1a[c] - m1[c]) * s1 + be1[c];
  a1[c]  = av;
  b1v[c] = bv;
  if (c < 64){
    float acc = 0.f;
    for (int d = 0; d < 128; ++d) acc = fmaf(b1b[d], w2a[d*64 + c], acc);
    c12[c] = acc;
    float s2 = g2[c] * rsqrtf(v2[c] + BN_EPS);
    A2[c] = s2;
    B2[c] = (b2a[c] - m2[c]) * s2 + be2[c];
  }
  float bp;
  if (av == 0.f) bp = 1e30f;
  else bp = fminf(fmaxf(-bv/av, -1e30f), 1e30f);
  bpl[c] = bp;
  __syncthreads();
  int rank = 0;
  for (int j = 0; j < 256; ++j){
    float bj = bpl[j];
    rank += (bj < bp) || (bj == bp && j < c);
  }
  sorted_p[rank] = bp;
  perm[rank] = c;
}

// W12 = w1b[256,128] @ w2a[128,64]
__global__ void prep_w12(const float* __restrict__ w1b, const float* __restrict__ w2a,
                         float* __restrict__ W12){
  int idx = blockIdx.x*256 + threadIdx.x;   // 16384 threads
  int c = idx >> 6, k = idx & 63;
  float acc = 0.f;
  for (int d = 0; d < 128; ++d) acc = fmaf(w1b[c*128 + d], w2a[d*64 + k], acc);
  W12[idx] = acc;
}

// w2bT[k][c] = w2b[c][k]
__global__ void prep_w2bT(const float* __restrict__ w2b, float* __restrict__ w2bT){
  int idx = blockIdx.x*256 + threadIdx.x;   // 4096
  int c = idx >> 6, k = idx & 63;
  w2bT[k*64 + c] = w2b[c*64 + k];
}

// ---------- build piecewise-linear table AB[257][128] (f32) — PARALLEL ----------
// row m: cols 0..63 = A_k, cols 64..127 = B_k (B base includes c12).
// f32, NOT bf16: per-(interval,channel) rounding bias is systematic and
// accumulates LINEARLY over ~33 same-interval neighbors (round-9 failure).
__global__ __launch_bounds__(256) void build_ab_par(const float* __restrict__ a1, const float* __restrict__ b1v,
                                                    const float* __restrict__ W12, const float* __restrict__ c12,
                                                    const int* __restrict__ perm, float* __restrict__ AB){
  __shared__ float sm[256];
  int col = blockIdx.x;        // 0..127
  int k = col & 63;
  bool isA = col < 64;
  int tm = threadIdx.x;        // 0..255
  float a0 = a1[tm], b0 = b1v[tm];
  float w0 = W12[tm*64 + k];
  bool act0 = (a0 < 0.f) || (a0 == 0.f && b0 > 0.f);
  float coeff0 = isA ? a0 : b0;
  sm[tm] = act0 ? coeff0*w0 : 0.f;
  __syncthreads();
  for (int off2 = 128; off2 > 0; off2 >>= 1){
    if (tm < off2) sm[tm] += sm[tm + off2];
    __syncthreads();
  }
  float base = sm[0] + (isA ? 0.f : c12[k]);
  __syncthreads();
  int g = perm[tm];
  float ag = a1[g], bg = b1v[g];
  float wg = W12[g*64 + k];
  float cg = isA ? ag : bg;
  float delta = (ag > 0.f) ? cg*wg : ((ag < 0.f) ? -cg*wg : 0.f);
  sm[tm] = delta;
  __syncthreads();
  for (int off = 1; off < 256; off <<= 1){
    float v = (tm >= off) ? sm[tm-off] : 0.f;
    __syncthreads();
    sm[tm] += v;
    __syncthreads();
  }
  AB[(tm+1)*128 + col] = base + sm[tm];
  if (tm == 0) AB[col] = base;
}

__global__ void init_gpos(int* __restrict__ gpos, int nb){
  int i = blockIdx.x*256 + threadIdx.x;
  if (i < nb) gpos[i] = i * SLACK;
}

// ---------- pass 1: bin edges by dst bucket (block-local counting sort) ----------
__global__ __launch_bounds__(512) void bin_edges(const int* __restrict__ ei, int* __restrict__ gpos,
                                                 uint32_t* __restrict__ binned, int E, int nb){
  __shared__ int hist[512];
  __shared__ int sc[512];
  __shared__ int cur[512];
  __shared__ int gbase[512];
  __shared__ uint32_t staged[TILE];
  __shared__ uint16_t bof[TILE];
  int t = threadIdx.x;
  int base = blockIdx.x * TILE;
  hist[t] = 0;
  __syncthreads();
  #pragma unroll
  for (int k = 0; k < TILE/512; ++k){
    int e = base + t + k*512;
    if (e < E) atomicAdd(&hist[ei[E + e] >> BSH], 1);
  }
  __syncthreads();
  int mycnt = hist[t];
  sc[t] = mycnt;
  __syncthreads();
  for (int off = 1; off < 512; off <<= 1){
    int v = (t >= off) ? sc[t-off] : 0;
    __syncthreads();
    sc[t] += v;
    __syncthreads();
  }
  int excl = sc[t] - mycnt;
  hist[t] = excl;
  cur[t]  = excl;
  if (t < nb && mycnt > 0) gbase[t] = atomicAdd(&gpos[t], mycnt);
  __syncthreads();
  #pragma unroll
  for (int k = 0; k < TILE/512; ++k){
    int e = base + t + k*512;
    if (e < E){
      int d = ei[E + e];
      int s = ei[e];
      int b = d >> BSH;
      int slot = atomicAdd(&cur[b], 1);
      staged[slot] = ((uint32_t)(d & (BW-1)) << 17) | (uint32_t)s;
      bof[slot] = (uint16_t)b;
    }
  }
  __syncthreads();
  int tileCount = min(TILE, E - base);
  for (int i = t; i < tileCount; i += 512){
    int b = bof[i];
    binned[gbase[b] + (i - hist[b])] = staged[i];
  }
}

// ---------- exclusive scan of bucket counts -> global col base ----------
__global__ __launch_bounds__(512) void scan_buckets(const int* __restrict__ gpos, int* __restrict__ bucket_base,
                                                    int* __restrict__ rowstart, int nb, int n, int E){
  __shared__ int sm[512];
  int t = threadIdx.x;
  int c = (t < nb) ? (gpos[t] - t*SLACK) : 0;
  sm[t] = c; __syncthreads();
  for (int off = 1; off < 512; off <<= 1){
    int v = (t >= off) ? sm[t-off] : 0;
    __syncthreads();
    sm[t] += v;
    __syncthreads();
  }
  if (t < nb) bucket_base[t] = sm[t] - c;
  if (t == 0) rowstart[n] = E;
}

// ---------- pass 2: within-bucket sort by dst -> CSR (col + rowstart) ----------
__global__ __launch_bounds__(512) void sort_bucket(const uint32_t* __restrict__ binned, const int* __restrict__ gpos,
                                                   const int* __restrict__ bucket_base, int* __restrict__ rowstart,
                                                   int* __restrict__ col, int n){
  __shared__ int hist[BW];
  __shared__ int sc[BW];
  __shared__ int cur[BW];
  int b = blockIdx.x, t = threadIdx.x;
  int cnt = gpos[b] - b*SLACK;
  const uint32_t* src = binned + (size_t)b*SLACK;
  if (t < BW) hist[t] = 0;
  __syncthreads();
  for (int i = t; i < cnt; i += 512) atomicAdd(&hist[src[i] >> 17], 1);
  __syncthreads();
  if (t < BW) sc[t] = hist[t];
  __syncthreads();
  for (int off = 1; off < BW; off <<= 1){
    int v = (t < BW && t >= off) ? sc[t-off] : 0;
    __syncthreads();
    if (t < BW) sc[t] += v;
    __syncthreads();
  }
  int base = bucket_base[b];
  if (t < BW){
    int e = sc[t] - hist[t];
    cur[t] = base + e;
    int node = (b << BSH) + t;
    if (node < n) rowstart[node] = base + e;
  }
  __syncthreads();
  for (int i = t; i < cnt; i += 512){
    uint32_t e = src[i];
    int p = atomicAdd(&cur[e >> 17], 1);
    col[p] = (int)(e & 0x1FFFFu);
  }
}

// ---------- GIN1: per node compute scalar s and interval m only ----------
__global__ __launch_bounds__(256) void gin1_ms(const float* __restrict__ x,
    const int* __restrict__ rowstart, const int* __restrict__ col,
    const float* __restrict__ sorted_p, uint2* __restrict__ ms, int n){
  __shared__ float sp[256];
  sp[threadIdx.x] = sorted_p[threadIdx.x];
  __syncthreads();
  int tid = blockIdx.x*256 + threadIdx.x;
  int node = tid >> 2, sub = tid & 3;       // 4 lanes per node
  if (node >= n) return;
  int beg = rowstart[node], end = rowstart[node+1];
  float s = 0.f;
  for (int j = beg + sub; j < end; j += 4) s += x[col[j]];
  s += __shfl_xor(s, 1);
  s += __shfl_xor(s, 2);
  s += x[node];
  if (sub == 0){
    int lo = 0, hi = 256;
    while (lo < hi){
      int mid = (lo + hi) >> 1;
      if (sp[mid] <= s) lo = mid + 1; else hi = mid;
    }
    uint2 v; v.x = __float_as_uint(s); v.y = (uint32_t)lo;
    ms[node] = v;
  }
}

// per-edge accumulate: u[k] += A[m][k]*s + B[m][k] for this lane's 8 channels (f32 table)
static __device__ __forceinline__ void accAB(float* u, const float* __restrict__ AB,
                                             uint2 mv, int slot){
  float s = __uint_as_float(mv.x);
  const float4* ap = reinterpret_cast<const float4*>(AB + (size_t)mv.y*128 + slot*8);
  const float4* bp = reinterpret_cast<const float4*>(AB + (size_t)mv.y*128 + 64 + slot*8);
  float4 a0 = ap[0], a1 = ap[1], b0 = bp[0], b1 = bp[1];
  u[0] += fmaf(a0.x, s, b0.x);
  u[1] += fmaf(a0.y, s, b0.y);
  u[2] += fmaf(a0.z, s, b0.z);
  u[3] += fmaf(a0.w, s, b0.w);
  u[4] += fmaf(a1.x, s, b1.x);
  u[5] += fmaf(a1.y, s, b1.y);
  u[6] += fmaf(a1.z, s, b1.z);
  u[7] += fmaf(a1.w, s, b1.w);
}

// ---------- fused GIN2 aggregation + BN2 + ReLU + full head + log_softmax ----------
// 8 nodes/wave, 8 lanes/node (slot = lane&7 owns channels slot*8..slot*8+7)
__global__ __launch_bounds__(256) void agg_ms(const int* __restrict__ rowstart, const int* __restrict__ col,
    const uint2* __restrict__ ms, const float* __restrict__ AB,
    const float* __restrict__ A2, const float* __restrict__ B2,
    const float* __restrict__ w2bT, const float* __restrict__ b2b,
    const float* __restrict__ wl1, const float* __restrict__ bl1,
    const float* __restrict__ wl2, const float* __restrict__ bl2,
    float* __restrict__ out, int n){
  int tid = blockIdx.x*256 + threadIdx.x;
  int lane = threadIdx.x & 63;
  int node = ((tid >> 6) << 3) + (lane >> 3);
  int slot = lane & 7;
  bool valid = node < n;
  int nd = valid ? node : 0;
  int beg = rowstart[nd];
  int end = valid ? rowstart[nd+1] : beg;
  float u[8];
  #pragma unroll
  for (int q = 0; q < 8; ++q) u[q] = 0.f;
  accAB(u, AB, ms[nd], slot);              // self term
  for (int j = beg; __any(j < end); j += 2){
    bool a0 = j < end, a1 = j + 1 < end;
    int c0 = a0 ? col[j] : 0;
    int c1 = a1 ? col[j+1] : 0;
    uint2 m0, m1;
    if (a0) m0 = ms[c0];
    if (a1) m1 = ms[c1];
    if (a0) accAB(u, AB, m0, slot);
    if (a1) accAB(u, AB, m1, slot);
  }
  // BN2 + ReLU -> r (in place in u)
  {
    const float4* Ap = reinterpret_cast<const float4*>(A2 + slot*8);
    const float4* Bp = reinterpret_cast<const float4*>(B2 + slot*8);
    float4 A0 = Ap[0], A1 = Ap[1], B0 = Bp[0], B1 = Bp[1];
    u[0] = fmaxf(fmaf(u[0], A0.x, B0.x), 0.f);
    u[1] = fmaxf(fmaf(u[1], A0.y, B0.y), 0.f);
    u[2] = fmaxf(fmaf(u[2], A0.z, B0.z), 0.f);
    u[3] = fmaxf(fmaf(u[3], A0.w, B0.w), 0.f);
    u[4] = fmaxf(fmaf(u[4], A1.x, B1.x), 0.f);
    u[5] = fmaxf(fmaf(u[5], A1.y, B1.y), 0.f);
    u[6] = fmaxf(fmaf(u[6], A1.z, B1.z), 0.f);
    u[7] = fmaxf(fmaf(u[7], A1.w, B1.w), 0.f);
  }
  // head Linear(64,64): h8[kk] = sum_c r[c]*w2b[c][slot*8+kk] via rotate-shuffle
  float h8[8];
  #pragma unroll
  for (int q = 0; q < 8; ++q) h8[q] = 0.f;
  #pragma unroll
  for (int rot = 0; rot < 8; ++rot){
    int src = slot ^ rot;
    float rv0 = __shfl(u[0], src, 8);
    float rv1 = __shfl(u[1], src, 8);
    float rv2 = __shfl(u[2], src, 8);
    float rv3 = __shfl(u[3], src, 8);
    float rv4 = __shfl(u[4], src, 8);
    float rv5 = __shfl(u[5], src, 8);
    float rv6 = __shfl(u[6], src, 8);
    float rv7 = __shfl(u[7], src, 8);
    int cbase = src*8;
    #pragma unroll
    for (int kk = 0; kk < 8; ++kk){
      const float4* wp = reinterpret_cast<const float4*>(w2bT + (size_t)(slot*8+kk)*64 + cbase);
      float4 wa = wp[0], wb = wp[1];
      h8[kk] += rv0*wa.x + rv1*wa.y + rv2*wa.z + rv3*wa.w
              + rv4*wb.x + rv5*wb.y + rv6*wb.z + rv7*wb.w;
    }
  }
  {
    const float4* bb = reinterpret_cast<const float4*>(b2b + slot*8);
    float4 b0 = bb[0], b1 = bb[1];
    h8[0]+=b0.x; h8[1]+=b0.y; h8[2]+=b0.z; h8[3]+=b0.w;
    h8[4]+=b1.x; h8[5]+=b1.y; h8[6]+=b1.z; h8[7]+=b1.w;
  }
  // z[16] = h @ wl1 (partial per lane, butterfly-reduce over the 8 slots)
  float z16[16];
  #pragma unroll
  for (int j = 0; j < 16; ++j) z16[j] = 0.f;
  #pragma unroll
  for (int kk = 0; kk < 8; ++kk){
    float hk = h8[kk];
    const float4* wr = reinterpret_cast<const float4*>(wl1 + (size_t)(slot*8+kk)*16);
    float4 w0 = wr[0], w1 = wr[1], w2 = wr[2], w3 = wr[3];
    z16[0]+=hk*w0.x;  z16[1]+=hk*w0.y;  z16[2]+=hk*w0.z;  z16[3]+=hk*w0.w;
    z16[4]+=hk*w1.x;  z16[5]+=hk*w1.y;  z16[6]+=hk*w1.z;  z16[7]+=hk*w1.w;
    z16[8]+=hk*w2.x;  z16[9]+=hk*w2.y;  z16[10]+=hk*w2.z; z16[11]+=hk*w2.w;
    z16[12]+=hk*w3.x; z16[13]+=hk*w3.y; z16[14]+=hk*w3.z; z16[15]+=hk*w3.w;
  }
  #pragma unroll
  for (int mask = 1; mask < 8; mask <<= 1){
    #pragma unroll
    for (int j = 0; j < 16; ++j) z16[j] += __shfl_xor(z16[j], mask);
  }
  // lg[6] = relu(z+bl1) @ wl2 + bl2 ; log_softmax
  float lg[6];
  #pragma unroll
  for (int l = 0; l < 6; ++l) lg[l] = bl2[l];
  #pragma unroll
  for (int j = 0; j < 16; ++j){
    float zj = fmaxf(z16[j] + bl1[j], 0.f);
    const float* wr = wl2 + j*6;
    #pragma unroll
    for (int l = 0; l < 6; ++l) lg[l] = fmaf(zj, wr[l], lg[l]);
  }
  float mx = lg[0];
  #pragma unroll
  for (int l = 1; l < 6; ++l) mx = fmaxf(mx, lg[l]);
  float sum = 0.f;
  #pragma unroll
  for (int l = 0; l < 6; ++l) sum += expf(lg[l] - mx);
  float lse = mx + logf(sum);
  float vout = lg[0];
  vout = (slot == 1) ? lg[1] : vout;
  vout = (slot == 2) ? lg[2] : vout;
  vout = (slot == 3) ? lg[3] : vout;
  vout = (slot == 4) ? lg[4] : vout;
  vout = (slot == 5) ? lg[5] : vout;
  if (valid && slot < 6) out[(size_t)node*6 + slot] = vout - lse;
}

extern "C" void kernel_launch(void* const* d_in, const int* in_sizes, int n_in,
                              void* d_out, int out_size, void* d_ws, size_t ws_size,
                              hipStream_t stream){
  const float* x   = (const float*)d_in[0];
  const int*   ei  = (const int*)d_in[1];
  const float* w1a = (const float*)d_in[2];
  const float* b1a = (const float*)d_in[3];
  const float* g1  = (const float*)d_in[4];
  const float* be1 = (const float*)d_in[5];
  const float* m1  = (const float*)d_in[6];
  const float* v1  = (const float*)d_in[7];
  const float* w1b = (const float*)d_in[8];
  const float* b1b = (const float*)d_in[9];
  const float* w2a = (const float*)d_in[10];
  const float* b2a = (const float*)d_in[11];
  const float* g2  = (const float*)d_in[12];
  const float* be2 = (const float*)d_in[13];
  const float* m2  = (const float*)d_in[14];
  const float* v2  = (const float*)d_in[15];
  const float* w2b = (const float*)d_in[16];
  const float* b2b = (const float*)d_in[17];
  const float* wl1 = (const float*)d_in[18];
  const float* bl1 = (const float*)d_in[19];
  const float* wl2 = (const float*)d_in[20];
  const float* bl2 = (const float*)d_in[21];
  float* out = (float*)d_out;
  int n = in_sizes[0];        // N
  int E = in_sizes[1] / 2;    // edges
  int nb = (n + BW - 1) >> BSH;

  char* ws = (char*)d_ws;
  size_t off = 0;
  auto carve = [&](size_t bytes)->char*{ char* p = ws + off; off += (bytes + 255) & ~(size_t)255; return p; };
  float* a1   = (float*)carve(256*4);
  float* b1v  = (float*)carve(256*4);
  float* c12  = (float*)carve(64*4);
  float* A2   = (float*)carve(64*4);
  float* B2   = (float*)carve(64*4);
  float* W12  = (float*)carve(16384*4);
  float* w2bT = (float*)carve(4096*4);
  float* sorted_p = (float*)carve(256*4);
  int*   perm = (int*)carve(256*4);
  float* AB   = (float*)carve(257*128*4);
  int* gpos   = (int*)carve((size_t)nb*4);
  int* bucket_base = (int*)carve((size_t)nb*4);
  int* rowstart = (int*)carve((size_t)(n+1)*4);
  int* col    = (int*)carve((size_t)E*4);
  uint32_t* binned = (uint32_t*)carve((size_t)nb*SLACK*4);
  uint2* ms   = (uint2*)carve((size_t)n*8);

  prep_small<<<1, 256, 0, stream>>>(w1a,b1a,g1,be1,m1,v1,b1b,w2a,b2a,g2,be2,m2,v2,
                                    a1,b1v,c12,A2,B2,sorted_p,perm);
  prep_w12<<<64, 256, 0, stream>>>(w1b, w2a, W12);
  prep_w2bT<<<16, 256, 0, stream>>>(w2b, w2bT);
  build_ab_par<<<128, 256, 0, stream>>>(a1, b1v, W12, c12, perm, AB);
  init_gpos<<<(nb + 255)/256, 256, 0, stream>>>(gpos, nb);
  bin_edges<<<(E + TILE - 1)/TILE, 512, 0, stream>>>(ei, gpos, binned, E, nb);
  scan_buckets<<<1, 512, 0, stream>>>(gpos, bucket_base, rowstart, nb, n, E);
  sort_bucket<<<nb, 512, 0, stream>>>(binned, gpos, bucket_base, rowstart, col, n);
  gin1_ms<<<((size_t)n*4 + 255)/256, 256, 0, stream>>>(x, rowstart, col, sorted_p, ms, n);
  agg_ms<<<(n + 31)/32, 256, 0, stream>>>(rowstart, col, ms, AB, A2, B2,
                                          w2bT, b2b, wl1, bl1, wl2, bl2, out, n);
}

// Round 11
// 413.005 us; speedup vs baseline: 1.0101x; 1.0101x over previous
//
#include <hip/hip_runtime.h>
#include <stdint.h>

#define BN_EPS 1e-5f
#define BW    256        // nodes per bucket
#define BSH   8          // log2(BW)
#define SLACK 10240      // entries reserved per bucket (mean ~8184, huge margin)
#define TILE  4096       // edges per binning block

static __device__ __forceinline__ uint32_t bf16bits(float f){
  uint32_t u = __float_as_uint(f);
  return (u + 0x7fffu + ((u>>16)&1u)) >> 16;
}
static __device__ __forceinline__ float bf16tof(uint32_t us){
  return __uint_as_float(us<<16);
}
static __device__ __forceinline__ void acc8(float* acc, uint4 v){
  acc[0]+=bf16tof(v.x&0xFFFFu); acc[1]+=bf16tof(v.x>>16);
  acc[2]+=bf16tof(v.y&0xFFFFu); acc[3]+=bf16tof(v.y>>16);
  acc[4]+=bf16tof(v.z&0xFFFFu); acc[5]+=bf16tof(v.z>>16);
  acc[6]+=bf16tof(v.w&0xFFFFu); acc[7]+=bf16tof(v.w>>16);
}

// ---------- weight precompute + breakpoint sort ----------
__global__ __launch_bounds__(256) void prep_small(const float* __restrict__ w1a, const float* __restrict__ b1a,
                           const float* __restrict__ g1,  const float* __restrict__ be1,
                           const float* __restrict__ m1,  const float* __restrict__ v1,
                           const float* __restrict__ b1b, const float* __restrict__ w2a,
                           const float* __restrict__ b2a, const float* __restrict__ g2,
                           const float* __restrict__ be2, const float* __restrict__ m2,
                           const float* __restrict__ v2,
                           float* __restrict__ a1, float* __restrict__ b1v,
                           float* __restrict__ c12, float* __restrict__ A2, float* __restrict__ B2,
                           float* __restrict__ sorted_p, int* __restrict__ perm){
  __shared__ float bpl[256];
  int c = threadIdx.x;
  float s1 = g1[c] * rsqrtf(v1[c] + BN_EPS);
  float av = w1a[c] * s1;
  float bv = (b1a[c] - m1[c]) * s1 + be1[c];
  a1[c]  = av;
  b1v[c] = bv;
  if (c < 64){
    float acc = 0.f;
    for (int d = 0; d < 128; ++d) acc = fmaf(b1b[d], w2a[d*64 + c], acc);
    c12[c] = acc;
    float s2 = g2[c] * rsqrtf(v2[c] + BN_EPS);
    A2[c] = s2;
    B2[c] = (b2a[c] - m2[c]) * s2 + be2[c];
  }
  float bp;
  if (av == 0.f) bp = 1e30f;
  else bp = fminf(fmaxf(-bv/av, -1e30f), 1e30f);
  bpl[c] = bp;
  __syncthreads();
  int rank = 0;
  for (int j = 0; j < 256; ++j){
    float bj = bpl[j];
    rank += (bj < bp) || (bj == bp && j < c);
  }
  sorted_p[rank] = bp;
  perm[rank] = c;
}

// W12 = w1b[256,128] @ w2a[128,64]
__global__ void prep_w12(const float* __restrict__ w1b, const float* __restrict__ w2a,
                         float* __restrict__ W12){
  int idx = blockIdx.x*256 + threadIdx.x;   // 16384 threads
  int c = idx >> 6, k = idx & 63;
  float acc = 0.f;
  for (int d = 0; d < 128; ++d) acc = fmaf(w1b[c*128 + d], w2a[d*64 + k], acc);
  W12[idx] = acc;
}

// w2bT[k][c] = w2b[c][k]
__global__ void prep_w2bT(const float* __restrict__ w2b, float* __restrict__ w2bT){
  int idx = blockIdx.x*256 + threadIdx.x;   // 4096
  int c = idx >> 6, k = idx & 63;
  w2bT[k*64 + c] = w2b[c*64 + k];
}

// ---------- build piecewise-linear table AB[257][128] (f32) — PARALLEL ----------
__global__ __launch_bounds__(256) void build_ab_par(const float* __restrict__ a1, const float* __restrict__ b1v,
                                                    const float* __restrict__ W12, const float* __restrict__ c12,
                                                    const int* __restrict__ perm, float* __restrict__ AB){
  __shared__ float sm[256];
  int col = blockIdx.x;        // 0..127
  int k = col & 63;
  bool isA = col < 64;
  int tm = threadIdx.x;        // 0..255
  float a0 = a1[tm], b0 = b1v[tm];
  float w0 = W12[tm*64 + k];
  bool act0 = (a0 < 0.f) || (a0 == 0.f && b0 > 0.f);
  float coeff0 = isA ? a0 : b0;
  sm[tm] = act0 ? coeff0*w0 : 0.f;
  __syncthreads();
  for (int off2 = 128; off2 > 0; off2 >>= 1){
    if (tm < off2) sm[tm] += sm[tm + off2];
    __syncthreads();
  }
  float base = sm[0] + (isA ? 0.f : c12[k]);
  __syncthreads();
  int g = perm[tm];
  float ag = a1[g], bg = b1v[g];
  float wg = W12[g*64 + k];
  float cg = isA ? ag : bg;
  float delta = (ag > 0.f) ? cg*wg : ((ag < 0.f) ? -cg*wg : 0.f);
  sm[tm] = delta;
  __syncthreads();
  for (int off = 1; off < 256; off <<= 1){
    float v = (tm >= off) ? sm[tm-off] : 0.f;
    __syncthreads();
    sm[tm] += v;
    __syncthreads();
  }
  AB[(tm+1)*128 + col] = base + sm[tm];
  if (tm == 0) AB[col] = base;
}

__global__ void init_gpos(int* __restrict__ gpos, int nb){
  int i = blockIdx.x*256 + threadIdx.x;
  if (i < nb) gpos[i] = i * SLACK;
}

// ---------- pass 1: bin edges by dst bucket (block-local counting sort) ----------
__global__ __launch_bounds__(512) void bin_edges(const int* __restrict__ ei, int* __restrict__ gpos,
                                                 uint32_t* __restrict__ binned, int E, int nb){
  __shared__ int hist[512];
  __shared__ int sc[512];
  __shared__ int cur[512];
  __shared__ int gbase[512];
  __shared__ uint32_t staged[TILE];
  __shared__ uint16_t bof[TILE];
  int t = threadIdx.x;
  int base = blockIdx.x * TILE;
  hist[t] = 0;
  __syncthreads();
  #pragma unroll
  for (int k = 0; k < TILE/512; ++k){
    int e = base + t + k*512;
    if (e < E) atomicAdd(&hist[ei[E + e] >> BSH], 1);
  }
  __syncthreads();
  int mycnt = hist[t];
  sc[t] = mycnt;
  __syncthreads();
  for (int off = 1; off < 512; off <<= 1){
    int v = (t >= off) ? sc[t-off] : 0;
    __syncthreads();
    sc[t] += v;
    __syncthreads();
  }
  int excl = sc[t] - mycnt;
  hist[t] = excl;
  cur[t]  = excl;
  if (t < nb && mycnt > 0) gbase[t] = atomicAdd(&gpos[t], mycnt);
  __syncthreads();
  #pragma unroll
  for (int k = 0; k < TILE/512; ++k){
    int e = base + t + k*512;
    if (e < E){
      int d = ei[E + e];
      int s = ei[e];
      int b = d >> BSH;
      int slot = atomicAdd(&cur[b], 1);
      staged[slot] = ((uint32_t)(d & (BW-1)) << 17) | (uint32_t)s;
      bof[slot] = (uint16_t)b;
    }
  }
  __syncthreads();
  int tileCount = min(TILE, E - base);
  for (int i = t; i < tileCount; i += 512){
    int b = bof[i];
    binned[gbase[b] + (i - hist[b])] = staged[i];
  }
}

// ---------- exclusive scan of bucket counts -> global col base ----------
__global__ __launch_bounds__(512) void scan_buckets(const int* __restrict__ gpos, int* __restrict__ bucket_base,
                                                    int* __restrict__ rowstart, int nb, int n, int E){
  __shared__ int sm[512];
  int t = threadIdx.x;
  int c = (t < nb) ? (gpos[t] - t*SLACK) : 0;
  sm[t] = c; __syncthreads();
  for (int off = 1; off < 512; off <<= 1){
    int v = (t >= off) ? sm[t-off] : 0;
    __syncthreads();
    sm[t] += v;
    __syncthreads();
  }
  if (t < nb) bucket_base[t] = sm[t] - c;
  if (t == 0) rowstart[n] = E;
}

// ---------- pass 2: within-bucket sort by dst -> CSR (col + rowstart) ----------
__global__ __launch_bounds__(512) void sort_bucket(const uint32_t* __restrict__ binned, const int* __restrict__ gpos,
                                                   const int* __restrict__ bucket_base, int* __restrict__ rowstart,
                                                   int* __restrict__ col, int n){
  __shared__ int hist[BW];
  __shared__ int sc[BW];
  __shared__ int cur[BW];
  int b = blockIdx.x, t = threadIdx.x;
  int cnt = gpos[b] - b*SLACK;
  const uint32_t* src = binned + (size_t)b*SLACK;
  if (t < BW) hist[t] = 0;
  __syncthreads();
  for (int i = t; i < cnt; i += 512) atomicAdd(&hist[src[i] >> 17], 1);
  __syncthreads();
  if (t < BW) sc[t] = hist[t];
  __syncthreads();
  for (int off = 1; off < BW; off <<= 1){
    int v = (t < BW && t >= off) ? sc[t-off] : 0;
    __syncthreads();
    if (t < BW) sc[t] += v;
    __syncthreads();
  }
  int base = bucket_base[b];
  if (t < BW){
    int e = sc[t] - hist[t];
    cur[t] = base + e;
    int node = (b << BSH) + t;
    if (node < n) rowstart[node] = base + e;
  }
  __syncthreads();
  for (int i = t; i < cnt; i += 512){
    uint32_t e = src[i];
    int p = atomicAdd(&cur[e >> 17], 1);
    col[p] = (int)(e & 0x1FFFFu);
  }
}

// ---------- GIN1 via piecewise-linear table: 4 lanes/node, writes t bf16 ----------
__global__ __launch_bounds__(256) void gin1_pwl(const float* __restrict__ x,
    const int* __restrict__ rowstart, const int* __restrict__ col,
    const float* __restrict__ sorted_p, const float* __restrict__ AB,
    unsigned short* __restrict__ t, int n){
  __shared__ float sp[256];
  sp[threadIdx.x] = sorted_p[threadIdx.x];
  __syncthreads();
  int tid = blockIdx.x*256 + threadIdx.x;
  int node = tid >> 2, sub = tid & 3;       // 4 lanes per node, lane=16 channels
  if (node >= n) return;
  int beg = rowstart[node], end = rowstart[node+1];
  float s = 0.f;
  for (int j = beg + sub; j < end; j += 4) s += x[col[j]];
  s += __shfl_xor(s, 1);
  s += __shfl_xor(s, 2);
  s += x[node];
  int lo = 0, hi = 256;
  while (lo < hi){
    int mid = (lo + hi) >> 1;
    if (sp[mid] <= s) lo = mid + 1; else hi = mid;
  }
  const float* ab = AB + lo*128 + sub*16;
  const float4* Ap = reinterpret_cast<const float4*>(ab);
  const float4* Bp = reinterpret_cast<const float4*>(ab + 64);
  uint4 o0, o1;
  {
    float4 A0 = Ap[0], A1 = Ap[1], B0 = Bp[0], B1 = Bp[1];
    o0.x = bf16bits(fmaf(A0.x,s,B0.x)) | (bf16bits(fmaf(A0.y,s,B0.y))<<16);
    o0.y = bf16bits(fmaf(A0.z,s,B0.z)) | (bf16bits(fmaf(A0.w,s,B0.w))<<16);
    o0.z = bf16bits(fmaf(A1.x,s,B1.x)) | (bf16bits(fmaf(A1.y,s,B1.y))<<16);
    o0.w = bf16bits(fmaf(A1.z,s,B1.z)) | (bf16bits(fmaf(A1.w,s,B1.w))<<16);
  }
  {
    float4 A2v = Ap[2], A3 = Ap[3], B2v = Bp[2], B3 = Bp[3];
    o1.x = bf16bits(fmaf(A2v.x,s,B2v.x)) | (bf16bits(fmaf(A2v.y,s,B2v.y))<<16);
    o1.y = bf16bits(fmaf(A2v.z,s,B2v.z)) | (bf16bits(fmaf(A2v.w,s,B2v.w))<<16);
    o1.z = bf16bits(fmaf(A3.x,s,B3.x)) | (bf16bits(fmaf(A3.y,s,B3.y))<<16);
    o1.w = bf16bits(fmaf(A3.z,s,B3.z)) | (bf16bits(fmaf(A3.w,s,B3.w))<<16);
  }
  uint4* dst = reinterpret_cast<uint4*>(t + (size_t)node*64 + sub*16);
  dst[0] = o0;
  dst[1] = o1;
}

// ---------- fused: GIN2 gather (t-rows) + BN2 + ReLU + head + log_softmax ----------
// 8 nodes/wave, 8 lanes/node (slot = lane&7 owns channels slot*8..slot*8+7)
__global__ __launch_bounds__(256) void agg_head(const int* __restrict__ rowstart, const int* __restrict__ col,
    const unsigned short* __restrict__ t,
    const float* __restrict__ A2, const float* __restrict__ B2,
    const float* __restrict__ w2bT, const float* __restrict__ b2b,
    const float* __restrict__ wl1, const float* __restrict__ bl1,
    const float* __restrict__ wl2, const float* __restrict__ bl2,
    float* __restrict__ out, int n){
  int tid = blockIdx.x*256 + threadIdx.x;
  int lane = threadIdx.x & 63;
  int node = ((tid >> 6) << 3) + (lane >> 3);
  int slot = lane & 7;
  bool valid = node < n;
  int nd = valid ? node : 0;
  int beg = rowstart[nd];
  int end = valid ? rowstart[nd+1] : beg;
  float u[8];
  {  // self row
    uint4 v = *reinterpret_cast<const uint4*>(t + (size_t)nd*64 + slot*8);
    u[0]=bf16tof(v.x&0xFFFFu); u[1]=bf16tof(v.x>>16);
    u[2]=bf16tof(v.y&0xFFFFu); u[3]=bf16tof(v.y>>16);
    u[4]=bf16tof(v.z&0xFFFFu); u[5]=bf16tof(v.z>>16);
    u[6]=bf16tof(v.w&0xFFFFu); u[7]=bf16tof(v.w>>16);
  }
  for (int j = beg; __any(j < end); j += 2){
    bool a0 = j < end, a1 = j + 1 < end;
    int c0 = a0 ? col[j] : 0;
    int c1 = a1 ? col[j+1] : 0;
    uint4 w0, w1;
    if (a0) w0 = *reinterpret_cast<const uint4*>(t + (size_t)c0*64 + slot*8);
    if (a1) w1 = *reinterpret_cast<const uint4*>(t + (size_t)c1*64 + slot*8);
    if (a0) acc8(u, w0);
    if (a1) acc8(u, w1);
  }
  // BN2 + ReLU -> r (in place in u)
  {
    const float4* Ap = reinterpret_cast<const float4*>(A2 + slot*8);
    const float4* Bp = reinterpret_cast<const float4*>(B2 + slot*8);
    float4 A0 = Ap[0], A1 = Ap[1], B0 = Bp[0], B1 = Bp[1];
    u[0] = fmaxf(fmaf(u[0], A0.x, B0.x), 0.f);
    u[1] = fmaxf(fmaf(u[1], A0.y, B0.y), 0.f);
    u[2] = fmaxf(fmaf(u[2], A0.z, B0.z), 0.f);
    u[3] = fmaxf(fmaf(u[3], A0.w, B0.w), 0.f);
    u[4] = fmaxf(fmaf(u[4], A1.x, B1.x), 0.f);
    u[5] = fmaxf(fmaf(u[5], A1.y, B1.y), 0.f);
    u[6] = fmaxf(fmaf(u[6], A1.z, B1.z), 0.f);
    u[7] = fmaxf(fmaf(u[7], A1.w, B1.w), 0.f);
  }
  // head Linear(64,64): h8[kk] = sum_c r[c]*w2b[c][slot*8+kk] via rotate-shuffle
  float h8[8];
  #pragma unroll
  for (int q = 0; q < 8; ++q) h8[q] = 0.f;
  #pragma unroll
  for (int rot = 0; rot < 8; ++rot){
    int src = slot ^ rot;
    float rv0 = __shfl(u[0], src, 8);
    float rv1 = __shfl(u[1], src, 8);
    float rv2 = __shfl(u[2], src, 8);
    float rv3 = __shfl(u[3], src, 8);
    float rv4 = __shfl(u[4], src, 8);
    float rv5 = __shfl(u[5], src, 8);
    float rv6 = __shfl(u[6], src, 8);
    float rv7 = __shfl(u[7], src, 8);
    int cbase = src*8;
    #pragma unroll
    for (int kk = 0; kk < 8; ++kk){
      const float4* wp = reinterpret_cast<const float4*>(w2bT + (size_t)(slot*8+kk)*64 + cbase);
      float4 wa = wp[0], wb = wp[1];
      h8[kk] += rv0*wa.x + rv1*wa.y + rv2*wa.z + rv3*wa.w
              + rv4*wb.x + rv5*wb.y + rv6*wb.z + rv7*wb.w;
    }
  }
  {
    const float4* bb = reinterpret_cast<const float4*>(b2b + slot*8);
    float4 b0 = bb[0], b1 = bb[1];
    h8[0]+=b0.x; h8[1]+=b0.y; h8[2]+=b0.z; h8[3]+=b0.w;
    h8[4]+=b1.x; h8[5]+=b1.y; h8[6]+=b1.z; h8[7]+=b1.w;
  }
  // z[16] = h @ wl1 (partial per lane, butterfly-reduce over the 8 slots)
  float z16[16];
  #pragma unroll
  for (int j = 0; j < 16; ++j) z16[j] = 0.f;
  #pragma unroll
  for (int kk = 0; kk < 8; ++kk){
    float hk = h8[kk];
    const float4* wr = reinterpret_cast<const float4*>(wl1 + (size_t)(slot*8+kk)*16);
    float4 w0 = wr[0], w1 = wr[1], w2 = wr[2], w3 = wr[3];
    z16[0]+=hk*w0.x;  z16[1]+=hk*w0.y;  z16[2]+=hk*w0.z;  z16[3]+=hk*w0.w;
    z16[4]+=hk*w1.x;  z16[5]+=hk*w1.y;  z16[6]+=hk*w1.z;  z16[7]+=hk*w1.w;
    z16[8]+=hk*w2.x;  z16[9]+=hk*w2.y;  z16[10]+=hk*w2.z; z16[11]+=hk*w2.w;
    z16[12]+=hk*w3.x; z16[13]+=hk*w3.y; z16[14]+=hk*w3.z; z16[15]+=hk*w3.w;
  }
  #pragma unroll
  for (int mask = 1; mask < 8; mask <<= 1){
    #pragma unroll
    for (int j = 0; j < 16; ++j) z16[j] += __shfl_xor(z16[j], mask);
  }
  // lg[6] = relu(z+bl1) @ wl2 + bl2 ; log_softmax
  float lg[6];
  #pragma unroll
  for (int l = 0; l < 6; ++l) lg[l] = bl2[l];
  #pragma unroll
  for (int j = 0; j < 16; ++j){
    float zj = fmaxf(z16[j] + bl1[j], 0.f);
    const float* wr = wl2 + j*6;
    #pragma unroll
    for (int l = 0; l < 6; ++l) lg[l] = fmaf(zj, wr[l], lg[l]);
  }
  float mx = lg[0];
  #pragma unroll
  for (int l = 1; l < 6; ++l) mx = fmaxf(mx, lg[l]);
  float sum = 0.f;
  #pragma unroll
  for (int l = 0; l < 6; ++l) sum += expf(lg[l] - mx);
  float lse = mx + logf(sum);
  float vout = lg[0];
  vout = (slot == 1) ? lg[1] : vout;
  vout = (slot == 2) ? lg[2] : vout;
  vout = (slot == 3) ? lg[3] : vout;
  vout = (slot == 4) ? lg[4] : vout;
  vout = (slot == 5) ? lg[5] : vout;
  if (valid && slot < 6) out[(size_t)node*6 + slot] = vout - lse;
}

extern "C" void kernel_launch(void* const* d_in, const int* in_sizes, int n_in,
                              void* d_out, int out_size, void* d_ws, size_t ws_size,
                              hipStream_t stream){
  const float* x   = (const float*)d_in[0];
  const int*   ei  = (const int*)d_in[1];
  const float* w1a = (const float*)d_in[2];
  const float* b1a = (const float*)d_in[3];
  const float* g1  = (const float*)d_in[4];
  const float* be1 = (const float*)d_in[5];
  const float* m1  = (const float*)d_in[6];
  const float* v1  = (const float*)d_in[7];
  const float* w1b = (const float*)d_in[8];
  const float* b1b = (const float*)d_in[9];
  const float* w2a = (const float*)d_in[10];
  const float* b2a = (const float*)d_in[11];
  const float* g2  = (const float*)d_in[12];
  const float* be2 = (const float*)d_in[13];
  const float* m2  = (const float*)d_in[14];
  const float* v2  = (const float*)d_in[15];
  const float* w2b = (const float*)d_in[16];
  const float* b2b = (const float*)d_in[17];
  const float* wl1 = (const float*)d_in[18];
  const float* bl1 = (const float*)d_in[19];
  const float* wl2 = (const float*)d_in[20];
  const float* bl2 = (const float*)d_in[21];
  float* out = (float*)d_out;
  int n = in_sizes[0];        // N
  int E = in_sizes[1] / 2;    // edges
  int nb = (n + BW - 1) >> BSH;

  char* ws = (char*)d_ws;
  size_t off = 0;
  auto carve = [&](size_t bytes)->char*{ char* p = ws + off; off += (bytes + 255) & ~(size_t)255; return p; };
  float* a1   = (float*)carve(256*4);
  float* b1v  = (float*)carve(256*4);
  float* c12  = (float*)carve(64*4);
  float* A2   = (float*)carve(64*4);
  float* B2   = (float*)carve(64*4);
  float* W12  = (float*)carve(16384*4);
  float* w2bT = (float*)carve(4096*4);
  float* sorted_p = (float*)carve(256*4);
  int*   perm = (int*)carve(256*4);
  float* AB   = (float*)carve(257*128*4);
  int* gpos   = (int*)carve((size_t)nb*4);
  int* bucket_base = (int*)carve((size_t)nb*4);
  int* rowstart = (int*)carve((size_t)(n+1)*4);
  int* col    = (int*)carve((size_t)E*4);
  uint32_t* binned = (uint32_t*)carve((size_t)nb*SLACK*4);
  unsigned short* t = (unsigned short*)binned;   // alias: binned dead after sort_bucket

  prep_small<<<1, 256, 0, stream>>>(w1a,b1a,g1,be1,m1,v1,b1b,w2a,b2a,g2,be2,m2,v2,
                                    a1,b1v,c12,A2,B2,sorted_p,perm);
  prep_w12<<<64, 256, 0, stream>>>(w1b, w2a, W12);
  prep_w2bT<<<16, 256, 0, stream>>>(w2b, w2bT);
  build_ab_par<<<128, 256, 0, stream>>>(a1, b1v, W12, c12, perm, AB);
  init_gpos<<<(nb + 255)/256, 256, 0, stream>>>(gpos, nb);
  bin_edges<<<(E + TILE - 1)/TILE, 512, 0, stream>>>(ei, gpos, binned, E, nb);
  scan_buckets<<<1, 512, 0, stream>>>(gpos, bucket_base, rowstart, nb, n, E);
  sort_bucket<<<nb, 512, 0, stream>>>(binned, gpos, bucket_base, rowstart, col, n);
  gin1_pwl<<<((size_t)n*4 + 255)/256, 256, 0, stream>>>(x, rowstart, col, sorted_p, AB, t, n);
  agg_head<<<(n + 31)/32, 256, 0, stream>>>(rowstart, col, t, A2, B2,
                                            w2bT, b2b, wl1, bl1, wl2, bl2, out, n);
}

// Round 12
// 402.477 us; speedup vs baseline: 1.0365x; 1.0262x over previous
//
#include <hip/hip_runtime.h>
#include <stdint.h>

#define BN_EPS 1e-5f
#define BW    256        // nodes per bucket
#define BSH   8          // log2(BW)
#define SLACK 10240      // entries reserved per bucket (mean ~8184, huge margin)
#define TILE  4096       // edges per binning block

static __device__ __forceinline__ uint32_t bf16bits(float f){
  uint32_t u = __float_as_uint(f);
  return (u + 0x7fffu + ((u>>16)&1u)) >> 16;
}
static __device__ __forceinline__ float bf16tof(uint32_t us){
  return __uint_as_float(us<<16);
}
static __device__ __forceinline__ void acc8(float* acc, uint4 v){
  acc[0]+=bf16tof(v.x&0xFFFFu); acc[1]+=bf16tof(v.x>>16);
  acc[2]+=bf16tof(v.y&0xFFFFu); acc[3]+=bf16tof(v.y>>16);
  acc[4]+=bf16tof(v.z&0xFFFFu); acc[5]+=bf16tof(v.z>>16);
  acc[6]+=bf16tof(v.w&0xFFFFu); acc[7]+=bf16tof(v.w>>16);
}

// ---------- weight precompute + breakpoint sort ----------
__global__ __launch_bounds__(256) void prep_small(const float* __restrict__ w1a, const float* __restrict__ b1a,
                           const float* __restrict__ g1,  const float* __restrict__ be1,
                           const float* __restrict__ m1,  const float* __restrict__ v1,
                           const float* __restrict__ b1b, const float* __restrict__ w2a,
                           const float* __restrict__ b2a, const float* __restrict__ g2,
                           const float* __restrict__ be2, const float* __restrict__ m2,
                           const float* __restrict__ v2,
                           float* __restrict__ a1, float* __restrict__ b1v,
                           float* __restrict__ c12, float* __restrict__ A2, float* __restrict__ B2,
                           float* __restrict__ sorted_p, int* __restrict__ perm){
  __shared__ float bpl[256];
  int c = threadIdx.x;
  float s1 = g1[c] * rsqrtf(v1[c] + BN_EPS);
  float av = w1a[c] * s1;
  float bv = (b1a[c] - m1[c]) * s1 + be1[c];
  a1[c]  = av;
  b1v[c] = bv;
  if (c < 64){
    float acc = 0.f;
    for (int d = 0; d < 128; ++d) acc = fmaf(b1b[d], w2a[d*64 + c], acc);
    c12[c] = acc;
    float s2 = g2[c] * rsqrtf(v2[c] + BN_EPS);
    A2[c] = s2;
    B2[c] = (b2a[c] - m2[c]) * s2 + be2[c];
  }
  float bp;
  if (av == 0.f) bp = 1e30f;
  else bp = fminf(fmaxf(-bv/av, -1e30f), 1e30f);
  bpl[c] = bp;
  __syncthreads();
  int rank = 0;
  for (int j = 0; j < 256; ++j){
    float bj = bpl[j];
    rank += (bj < bp) || (bj == bp && j < c);
  }
  sorted_p[rank] = bp;
  perm[rank] = c;
}

// W12 = w1b[256,128] @ w2a[128,64]
__global__ void prep_w12(const float* __restrict__ w1b, const float* __restrict__ w2a,
                         float* __restrict__ W12){
  int idx = blockIdx.x*256 + threadIdx.x;   // 16384 threads
  int c = idx >> 6, k = idx & 63;
  float acc = 0.f;
  for (int d = 0; d < 128; ++d) acc = fmaf(w1b[c*128 + d], w2a[d*64 + k], acc);
  W12[idx] = acc;
}

// w2bT[k][c] = w2b[c][k]
__global__ void prep_w2bT(const float* __restrict__ w2b, float* __restrict__ w2bT){
  int idx = blockIdx.x*256 + threadIdx.x;   // 4096
  int c = idx >> 6, k = idx & 63;
  w2bT[k*64 + c] = w2b[c*64 + k];
}

// ---------- build piecewise-linear table AB[257][128] (f32) — PARALLEL ----------
__global__ __launch_bounds__(256) void build_ab_par(const float* __restrict__ a1, const float* __restrict__ b1v,
                                                    const float* __restrict__ W12, const float* __restrict__ c12,
                                                    const int* __restrict__ perm, float* __restrict__ AB){
  __shared__ float sm[256];
  int col = blockIdx.x;        // 0..127
  int k = col & 63;
  bool isA = col < 64;
  int tm = threadIdx.x;        // 0..255
  float a0 = a1[tm], b0 = b1v[tm];
  float w0 = W12[tm*64 + k];
  bool act0 = (a0 < 0.f) || (a0 == 0.f && b0 > 0.f);
  float coeff0 = isA ? a0 : b0;
  sm[tm] = act0 ? coeff0*w0 : 0.f;
  __syncthreads();
  for (int off2 = 128; off2 > 0; off2 >>= 1){
    if (tm < off2) sm[tm] += sm[tm + off2];
    __syncthreads();
  }
  float base = sm[0] + (isA ? 0.f : c12[k]);
  __syncthreads();
  int g = perm[tm];
  float ag = a1[g], bg = b1v[g];
  float wg = W12[g*64 + k];
  float cg = isA ? ag : bg;
  float delta = (ag > 0.f) ? cg*wg : ((ag < 0.f) ? -cg*wg : 0.f);
  sm[tm] = delta;
  __syncthreads();
  for (int off = 1; off < 256; off <<= 1){
    float v = (tm >= off) ? sm[tm-off] : 0.f;
    __syncthreads();
    sm[tm] += v;
    __syncthreads();
  }
  AB[(tm+1)*128 + col] = base + sm[tm];
  if (tm == 0) AB[col] = base;
}

__global__ void init_gpos(int* __restrict__ gpos, int nb){
  int i = blockIdx.x*256 + threadIdx.x;
  if (i < nb) gpos[i] = i * SLACK;
}

// ---------- pass 1: bin edges by dst bucket (block-local counting sort) ----------
__global__ __launch_bounds__(512) void bin_edges(const int* __restrict__ ei, int* __restrict__ gpos,
                                                 uint32_t* __restrict__ binned, int E, int nb){
  __shared__ int hist[512];
  __shared__ int sc[512];
  __shared__ int cur[512];
  __shared__ int gbase[512];
  __shared__ uint32_t staged[TILE];
  __shared__ uint16_t bof[TILE];
  int t = threadIdx.x;
  int base = blockIdx.x * TILE;
  hist[t] = 0;
  __syncthreads();
  #pragma unroll
  for (int k = 0; k < TILE/512; ++k){
    int e = base + t + k*512;
    if (e < E) atomicAdd(&hist[ei[E + e] >> BSH], 1);
  }
  __syncthreads();
  int mycnt = hist[t];
  sc[t] = mycnt;
  __syncthreads();
  for (int off = 1; off < 512; off <<= 1){
    int v = (t >= off) ? sc[t-off] : 0;
    __syncthreads();
    sc[t] += v;
    __syncthreads();
  }
  int excl = sc[t] - mycnt;
  hist[t] = excl;
  cur[t]  = excl;
  if (t < nb && mycnt > 0) gbase[t] = atomicAdd(&gpos[t], mycnt);
  __syncthreads();
  #pragma unroll
  for (int k = 0; k < TILE/512; ++k){
    int e = base + t + k*512;
    if (e < E){
      int d = ei[E + e];
      int s = ei[e];
      int b = d >> BSH;
      int slot = atomicAdd(&cur[b], 1);
      staged[slot] = ((uint32_t)(d & (BW-1)) << 17) | (uint32_t)s;
      bof[slot] = (uint16_t)b;
    }
  }
  __syncthreads();
  int tileCount = min(TILE, E - base);
  for (int i = t; i < tileCount; i += 512){
    int b = bof[i];
    binned[gbase[b] + (i - hist[b])] = staged[i];
  }
}

// ---------- exclusive scan of bucket counts -> global col base ----------
__global__ __launch_bounds__(512) void scan_buckets(const int* __restrict__ gpos, int* __restrict__ bucket_base,
                                                    int* __restrict__ rowstart, int nb, int n, int E){
  __shared__ int sm[512];
  int t = threadIdx.x;
  int c = (t < nb) ? (gpos[t] - t*SLACK) : 0;
  sm[t] = c; __syncthreads();
  for (int off = 1; off < 512; off <<= 1){
    int v = (t >= off) ? sm[t-off] : 0;
    __syncthreads();
    sm[t] += v;
    __syncthreads();
  }
  if (t < nb) bucket_base[t] = sm[t] - c;
  if (t == 0) rowstart[n] = E;
}

// ---------- pass 2: within-bucket sort by dst -> CSR (col + rowstart) ----------
__global__ __launch_bounds__(512) void sort_bucket(const uint32_t* __restrict__ binned, const int* __restrict__ gpos,
                                                   const int* __restrict__ bucket_base, int* __restrict__ rowstart,
                                                   int* __restrict__ col, int n){
  __shared__ int hist[BW];
  __shared__ int sc[BW];
  __shared__ int cur[BW];
  int b = blockIdx.x, t = threadIdx.x;
  int cnt = gpos[b] - b*SLACK;
  const uint32_t* src = binned + (size_t)b*SLACK;
  if (t < BW) hist[t] = 0;
  __syncthreads();
  for (int i = t; i < cnt; i += 512) atomicAdd(&hist[src[i] >> 17], 1);
  __syncthreads();
  if (t < BW) sc[t] = hist[t];
  __syncthreads();
  for (int off = 1; off < BW; off <<= 1){
    int v = (t < BW && t >= off) ? sc[t-off] : 0;
    __syncthreads();
    if (t < BW) sc[t] += v;
    __syncthreads();
  }
  int base = bucket_base[b];
  if (t < BW){
    int e = sc[t] - hist[t];
    cur[t] = base + e;
    int node = (b << BSH) + t;
    if (node < n) rowstart[node] = base + e;
  }
  __syncthreads();
  for (int i = t; i < cnt; i += 512){
    uint32_t e = src[i];
    int p = atomicAdd(&cur[e >> 17], 1);
    col[p] = (int)(e & 0x1FFFFu);
  }
}

// ---------- GIN1 via piecewise-linear table: 4 lanes/node, writes t bf16 ----------
__global__ __launch_bounds__(256) void gin1_pwl(const float* __restrict__ x,
    const int* __restrict__ rowstart, const int* __restrict__ col,
    const float* __restrict__ sorted_p, const float* __restrict__ AB,
    unsigned short* __restrict__ t, int n){
  __shared__ float sp[256];
  sp[threadIdx.x] = sorted_p[threadIdx.x];
  __syncthreads();
  int tid = blockIdx.x*256 + threadIdx.x;
  int node = tid >> 2, sub = tid & 3;       // 4 lanes per node, lane=16 channels
  if (node >= n) return;
  int beg = rowstart[node], end = rowstart[node+1];
  float s = 0.f;
  for (int j = beg + sub; j < end; j += 4) s += x[col[j]];
  s += __shfl_xor(s, 1);
  s += __shfl_xor(s, 2);
  s += x[node];
  int lo = 0, hi = 256;
  while (lo < hi){
    int mid = (lo + hi) >> 1;
    if (sp[mid] <= s) lo = mid + 1; else hi = mid;
  }
  const float* ab = AB + lo*128 + sub*16;
  const float4* Ap = reinterpret_cast<const float4*>(ab);
  const float4* Bp = reinterpret_cast<const float4*>(ab + 64);
  uint4 o0, o1;
  {
    float4 A0 = Ap[0], A1 = Ap[1], B0 = Bp[0], B1 = Bp[1];
    o0.x = bf16bits(fmaf(A0.x,s,B0.x)) | (bf16bits(fmaf(A0.y,s,B0.y))<<16);
    o0.y = bf16bits(fmaf(A0.z,s,B0.z)) | (bf16bits(fmaf(A0.w,s,B0.w))<<16);
    o0.z = bf16bits(fmaf(A1.x,s,B1.x)) | (bf16bits(fmaf(A1.y,s,B1.y))<<16);
    o0.w = bf16bits(fmaf(A1.z,s,B1.z)) | (bf16bits(fmaf(A1.w,s,B1.w))<<16);
  }
  {
    float4 A2v = Ap[2], A3 = Ap[3], B2v = Bp[2], B3 = Bp[3];
    o1.x = bf16bits(fmaf(A2v.x,s,B2v.x)) | (bf16bits(fmaf(A2v.y,s,B2v.y))<<16);
    o1.y = bf16bits(fmaf(A2v.z,s,B2v.z)) | (bf16bits(fmaf(A2v.w,s,B2v.w))<<16);
    o1.z = bf16bits(fmaf(A3.x,s,B3.x)) | (bf16bits(fmaf(A3.y,s,B3.y))<<16);
    o1.w = bf16bits(fmaf(A3.z,s,B3.z)) | (bf16bits(fmaf(A3.w,s,B3.w))<<16);
  }
  uint4* dst = reinterpret_cast<uint4*>(t + (size_t)node*64 + sub*16);
  dst[0] = o0;
  dst[1] = o1;
}

// ---------- GIN2 aggregation: 8 nodes/wave, 8 lanes/node, register accum ----------
// LEAN on purpose (VGPR 24, occ 60%, 2.5 TB/s): do NOT fuse head here (round-11 lesson).
__global__ __launch_bounds__(256) void agg8(const int* __restrict__ rowstart, const int* __restrict__ col,
                                            const unsigned short* __restrict__ t,
                                            const float* __restrict__ A2, const float* __restrict__ B2,
                                            unsigned short* __restrict__ r2, int n){
  int tid = blockIdx.x*256 + threadIdx.x;
  int lane = threadIdx.x & 63;
  int node = ((tid >> 6) << 3) + (lane >> 3);
  int slot = lane & 7;                      // 8-channel slot within the row
  bool valid = node < n;
  int beg = valid ? rowstart[node] : 0;
  int end = valid ? rowstart[node+1] : 0;
  float acc[8];
  {  // self row
    const uint4* trow = reinterpret_cast<const uint4*>(t + ((size_t)(valid ? node : 0))*64 + slot*8);
    uint4 v = *trow;
    acc[0]=bf16tof(v.x&0xFFFFu); acc[1]=bf16tof(v.x>>16);
    acc[2]=bf16tof(v.y&0xFFFFu); acc[3]=bf16tof(v.y>>16);
    acc[4]=bf16tof(v.z&0xFFFFu); acc[5]=bf16tof(v.z>>16);
    acc[6]=bf16tof(v.w&0xFFFFu); acc[7]=bf16tof(v.w>>16);
    if (!valid){
      #pragma unroll
      for (int q = 0; q < 8; ++q) acc[q] = 0.f;
    }
  }
  for (int j = beg; __any(j < end); j += 2){
    bool a0 = j < end, a1 = j + 1 < end;
    int s0 = a0 ? col[j] : 0;
    int s1 = a1 ? col[j+1] : 0;
    uint4 w0, w1;
    if (a0) w0 = *reinterpret_cast<const uint4*>(t + (size_t)s0*64 + slot*8);
    if (a1) w1 = *reinterpret_cast<const uint4*>(t + (size_t)s1*64 + slot*8);
    if (a0) acc8(acc, w0);
    if (a1) acc8(acc, w1);
  }
  if (valid){
    const float4* Ap = reinterpret_cast<const float4*>(A2 + slot*8);
    const float4* Bp = reinterpret_cast<const float4*>(B2 + slot*8);
    float4 A0 = Ap[0], A1 = Ap[1], B0 = Bp[0], B1 = Bp[1];
    float Av[8] = {A0.x,A0.y,A0.z,A0.w,A1.x,A1.y,A1.z,A1.w};
    float Bv[8] = {B0.x,B0.y,B0.z,B0.w,B1.x,B1.y,B1.z,B1.w};
    float r[8];
    #pragma unroll
    for (int q = 0; q < 8; ++q) r[q] = fmaxf(fmaf(acc[q], Av[q], Bv[q]), 0.f);
    uint4 o;
    o.x = bf16bits(r[0]) | (bf16bits(r[1])<<16);
    o.y = bf16bits(r[2]) | (bf16bits(r[3])<<16);
    o.z = bf16bits(r[4]) | (bf16bits(r[5])<<16);
    o.w = bf16bits(r[6]) | (bf16bits(r[7])<<16);
    *reinterpret_cast<uint4*>(r2 + (size_t)node*64 + slot*8) = o;
  }
}

// ---------- head: 8 lanes/node in-register, reads bf16 r2 (coalesced) ----------
__global__ __launch_bounds__(256) void head8(const unsigned short* __restrict__ r2,
    const float* __restrict__ w2bT, const float* __restrict__ b2b,
    const float* __restrict__ wl1, const float* __restrict__ bl1,
    const float* __restrict__ wl2, const float* __restrict__ bl2,
    float* __restrict__ out, int n){
  int tid = blockIdx.x*256 + threadIdx.x;
  int lane = threadIdx.x & 63;
  int node = ((tid >> 6) << 3) + (lane >> 3);
  int slot = lane & 7;
  bool valid = node < n;
  int nd = valid ? node : 0;
  float u[8];
  {
    uint4 v = *reinterpret_cast<const uint4*>(r2 + (size_t)nd*64 + slot*8);
    u[0]=bf16tof(v.x&0xFFFFu); u[1]=bf16tof(v.x>>16);
    u[2]=bf16tof(v.y&0xFFFFu); u[3]=bf16tof(v.y>>16);
    u[4]=bf16tof(v.z&0xFFFFu); u[5]=bf16tof(v.z>>16);
    u[6]=bf16tof(v.w&0xFFFFu); u[7]=bf16tof(v.w>>16);
  }
  // Linear(64,64): h8[kk] = sum_c r[c]*w2b[c][slot*8+kk] via rotate-shuffle
  float h8[8];
  #pragma unroll
  for (int q = 0; q < 8; ++q) h8[q] = 0.f;
  #pragma unroll
  for (int rot = 0; rot < 8; ++rot){
    int src = slot ^ rot;
    float rv0 = __shfl(u[0], src, 8);
    float rv1 = __shfl(u[1], src, 8);
    float rv2 = __shfl(u[2], src, 8);
    float rv3 = __shfl(u[3], src, 8);
    float rv4 = __shfl(u[4], src, 8);
    float rv5 = __shfl(u[5], src, 8);
    float rv6 = __shfl(u[6], src, 8);
    float rv7 = __shfl(u[7], src, 8);
    int cbase = src*8;
    #pragma unroll
    for (int kk = 0; kk < 8; ++kk){
      const float4* wp = reinterpret_cast<const float4*>(w2bT + (size_t)(slot*8+kk)*64 + cbase);
      float4 wa = wp[0], wb = wp[1];
      h8[kk] += rv0*wa.x + rv1*wa.y + rv2*wa.z + rv3*wa.w
              + rv4*wb.x + rv5*wb.y + rv6*wb.z + rv7*wb.w;
    }
  }
  {
    const float4* bb = reinterpret_cast<const float4*>(b2b + slot*8);
    float4 b0 = bb[0], b1 = bb[1];
    h8[0]+=b0.x; h8[1]+=b0.y; h8[2]+=b0.z; h8[3]+=b0.w;
    h8[4]+=b1.x; h8[5]+=b1.y; h8[6]+=b1.z; h8[7]+=b1.w;
  }
  // z[16] = h @ wl1 (partial per lane, butterfly-reduce over the 8 slots)
  float z16[16];
  #pragma unroll
  for (int j = 0; j < 16; ++j) z16[j] = 0.f;
  #pragma unroll
  for (int kk = 0; kk < 8; ++kk){
    float hk = h8[kk];
    const float4* wr = reinterpret_cast<const float4*>(wl1 + (size_t)(slot*8+kk)*16);
    float4 w0 = wr[0], w1 = wr[1], w2 = wr[2], w3 = wr[3];
    z16[0]+=hk*w0.x;  z16[1]+=hk*w0.y;  z16[2]+=hk*w0.z;  z16[3]+=hk*w0.w;
    z16[4]+=hk*w1.x;  z16[5]+=hk*w1.y;  z16[6]+=hk*w1.z;  z16[7]+=hk*w1.w;
    z16[8]+=hk*w2.x;  z16[9]+=hk*w2.y;  z16[10]+=hk*w2.z; z16[11]+=hk*w2.w;
    z16[12]+=hk*w3.x; z16[13]+=hk*w3.y; z16[14]+=hk*w3.z; z16[15]+=hk*w3.w;
  }
  #pragma unroll
  for (int mask = 1; mask < 8; mask <<= 1){
    #pragma unroll
    for (int j = 0; j < 16; ++j) z16[j] += __shfl_xor(z16[j], mask);
  }
  // lg[6] = relu(z+bl1) @ wl2 + bl2 ; log_softmax
  float lg[6];
  #pragma unroll
  for (int l = 0; l < 6; ++l) lg[l] = bl2[l];
  #pragma unroll
  for (int j = 0; j < 16; ++j){
    float zj = fmaxf(z16[j] + bl1[j], 0.f);
    const float* wr = wl2 + j*6;
    #pragma unroll
    for (int l = 0; l < 6; ++l) lg[l] = fmaf(zj, wr[l], lg[l]);
  }
  float mx = lg[0];
  #pragma unroll
  for (int l = 1; l < 6; ++l) mx = fmaxf(mx, lg[l]);
  float sum = 0.f;
  #pragma unroll
  for (int l = 0; l < 6; ++l) sum += expf(lg[l] - mx);
  float lse = mx + logf(sum);
  float vout = lg[0];
  vout = (slot == 1) ? lg[1] : vout;
  vout = (slot == 2) ? lg[2] : vout;
  vout = (slot == 3) ? lg[3] : vout;
  vout = (slot == 4) ? lg[4] : vout;
  vout = (slot == 5) ? lg[5] : vout;
  if (valid && slot < 6) out[(size_t)node*6 + slot] = vout - lse;
}

extern "C" void kernel_launch(void* const* d_in, const int* in_sizes, int n_in,
                              void* d_out, int out_size, void* d_ws, size_t ws_size,
                              hipStream_t stream){
  const float* x   = (const float*)d_in[0];
  const int*   ei  = (const int*)d_in[1];
  const float* w1a = (const float*)d_in[2];
  const float* b1a = (const float*)d_in[3];
  const float* g1  = (const float*)d_in[4];
  const float* be1 = (const float*)d_in[5];
  const float* m1  = (const float*)d_in[6];
  const float* v1  = (const float*)d_in[7];
  const float* w1b = (const float*)d_in[8];
  const float* b1b = (const float*)d_in[9];
  const float* w2a = (const float*)d_in[10];
  const float* b2a = (const float*)d_in[11];
  const float* g2  = (const float*)d_in[12];
  const float* be2 = (const float*)d_in[13];
  const float* m2  = (const float*)d_in[14];
  const float* v2  = (const float*)d_in[15];
  const float* w2b = (const float*)d_in[16];
  const float* b2b = (const float*)d_in[17];
  const float* wl1 = (const float*)d_in[18];
  const float* bl1 = (const float*)d_in[19];
  const float* wl2 = (const float*)d_in[20];
  const float* bl2 = (const float*)d_in[21];
  float* out = (float*)d_out;
  int n = in_sizes[0];        // N
  int E = in_sizes[1] / 2;    // edges
  int nb = (n + BW - 1) >> BSH;

  char* ws = (char*)d_ws;
  size_t off = 0;
  auto carve = [&](size_t bytes)->char*{ char* p = ws + off; off += (bytes + 255) & ~(size_t)255; return p; };
  float* a1   = (float*)carve(256*4);
  float* b1v  = (float*)carve(256*4);
  float* c12  = (float*)carve(64*4);
  float* A2   = (float*)carve(64*4);
  float* B2   = (float*)carve(64*4);
  float* W12  = (float*)carve(16384*4);
  float* w2bT = (float*)carve(4096*4);
  float* sorted_p = (float*)carve(256*4);
  int*   perm = (int*)carve(256*4);
  float* AB   = (float*)carve(257*128*4);
  int* gpos   = (int*)carve((size_t)nb*4);
  int* bucket_base = (int*)carve((size_t)nb*4);
  int* rowstart = (int*)carve((size_t)(n+1)*4);
  int* col    = (int*)carve((size_t)E*4);
  uint32_t* binned = (uint32_t*)carve((size_t)nb*SLACK*4);
  unsigned short* t  = (unsigned short*)binned;   // alias: binned dead after sort_bucket
  unsigned short* r2 = (unsigned short*)carve((size_t)n*64*2);

  prep_small<<<1, 256, 0, stream>>>(w1a,b1a,g1,be1,m1,v1,b1b,w2a,b2a,g2,be2,m2,v2,
                                    a1,b1v,c12,A2,B2,sorted_p,perm);
  prep_w12<<<64, 256, 0, stream>>>(w1b, w2a, W12);
  prep_w2bT<<<16, 256, 0, stream>>>(w2b, w2bT);
  build_ab_par<<<128, 256, 0, stream>>>(a1, b1v, W12, c12, perm, AB);
  init_gpos<<<(nb + 255)/256, 256, 0, stream>>>(gpos, nb);
  bin_edges<<<(E + TILE - 1)/TILE, 512, 0, stream>>>(ei, gpos, binned, E, nb);
  scan_buckets<<<1, 512, 0, stream>>>(gpos, bucket_base, rowstart, nb, n, E);
  sort_bucket<<<nb, 512, 0, stream>>>(binned, gpos, bucket_base, rowstart, col, n);
  gin1_pwl<<<((size_t)n*4 + 255)/256, 256, 0, stream>>>(x, rowstart, col, sorted_p, AB, t, n);
  agg8<<<(n + 31)/32, 256, 0, stream>>>(rowstart, col, t, A2, B2, r2, n);
  head8<<<(n + 31)/32, 256, 0, stream>>>(r2, w2bT, b2b, wl1, bl1, wl2, bl2, out, n);
}

// Round 13
// 293.186 us; speedup vs baseline: 1.4229x; 1.3728x over previous
//
#include <hip/hip_runtime.h>
#include <stdint.h>

#define BN_EPS 1e-5f
#define BW    256        // nodes per bucket
#define BSH   8          // log2(BW)
#define SLACK 10240      // entries reserved per bucket (mean ~8184, huge margin)
#define TILE  4096       // edges per binning block

static __device__ __forceinline__ uint32_t bf16bits(float f){
  uint32_t u = __float_as_uint(f);
  return (u + 0x7fffu + ((u>>16)&1u)) >> 16;
}
static __device__ __forceinline__ float bf16tof(uint32_t us){
  return __uint_as_float(us<<16);
}
static __device__ __forceinline__ void acc8(float* acc, uint4 v){
  acc[0]+=bf16tof(v.x&0xFFFFu); acc[1]+=bf16tof(v.x>>16);
  acc[2]+=bf16tof(v.y&0xFFFFu); acc[3]+=bf16tof(v.y>>16);
  acc[4]+=bf16tof(v.z&0xFFFFu); acc[5]+=bf16tof(v.z>>16);
  acc[6]+=bf16tof(v.w&0xFFFFu); acc[7]+=bf16tof(v.w>>16);
}

// ---------- weight precompute + breakpoint sort ----------
__global__ __launch_bounds__(256) void prep_small(const float* __restrict__ w1a, const float* __restrict__ b1a,
                           const float* __restrict__ g1,  const float* __restrict__ be1,
                           const float* __restrict__ m1,  const float* __restrict__ v1,
                           const float* __restrict__ b1b, const float* __restrict__ w2a,
                           const float* __restrict__ b2a, const float* __restrict__ g2,
                           const float* __restrict__ be2, const float* __restrict__ m2,
                           const float* __restrict__ v2,
                           float* __restrict__ a1, float* __restrict__ b1v,
                           float* __restrict__ c12, float* __restrict__ A2, float* __restrict__ B2,
                           float* __restrict__ sorted_p, int* __restrict__ perm){
  __shared__ float bpl[256];
  int c = threadIdx.x;
  float s1 = g1[c] * rsqrtf(v1[c] + BN_EPS);
  float av = w1a[c] * s1;
  float bv = (b1a[c] - m1[c]) * s1 + be1[c];
  a1[c]  = av;
  b1v[c] = bv;
  if (c < 64){
    float acc = 0.f;
    for (int d = 0; d < 128; ++d) acc = fmaf(b1b[d], w2a[d*64 + c], acc);
    c12[c] = acc;
    float s2 = g2[c] * rsqrtf(v2[c] + BN_EPS);
    A2[c] = s2;
    B2[c] = (b2a[c] - m2[c]) * s2 + be2[c];
  }
  float bp;
  if (av == 0.f) bp = 1e30f;
  else bp = fminf(fmaxf(-bv/av, -1e30f), 1e30f);
  bpl[c] = bp;
  __syncthreads();
  int rank = 0;
  for (int j = 0; j < 256; ++j){
    float bj = bpl[j];
    rank += (bj < bp) || (bj == bp && j < c);
  }
  sorted_p[rank] = bp;
  perm[rank] = c;
}

// W12 = w1b[256,128] @ w2a[128,64]
__global__ void prep_w12(const float* __restrict__ w1b, const float* __restrict__ w2a,
                         float* __restrict__ W12){
  int idx = blockIdx.x*256 + threadIdx.x;   // 16384 threads
  int c = idx >> 6, k = idx & 63;
  float acc = 0.f;
  for (int d = 0; d < 128; ++d) acc = fmaf(w1b[c*128 + d], w2a[d*64 + k], acc);
  W12[idx] = acc;
}

// ---------- fold head: Wbl[64][16] = w2b@wl1 ; cbl[16] = b2b@wl1 + bl1 ----------
// (no ReLU between w2b and wl1 -> exact algebra)
__global__ __launch_bounds__(256) void prep_head_fold(const float* __restrict__ w2b, const float* __restrict__ b2b,
                                                      const float* __restrict__ wl1, const float* __restrict__ bl1,
                                                      float* __restrict__ Wbl, float* __restrict__ cbl){
  int idx = blockIdx.x*256 + threadIdx.x;   // 1024 threads
  int c = idx >> 4, j = idx & 15;
  float acc = 0.f;
  for (int k = 0; k < 64; ++k) acc = fmaf(w2b[c*64 + k], wl1[k*16 + j], acc);
  Wbl[idx] = acc;
  if (c == 0){
    float a2 = 0.f;
    for (int k = 0; k < 64; ++k) a2 = fmaf(b2b[k], wl1[k*16 + j], a2);
    cbl[j] = a2 + bl1[j];
  }
}

// ---------- build piecewise-linear table AB[257][128] (f32) — PARALLEL ----------
__global__ __launch_bounds__(256) void build_ab_par(const float* __restrict__ a1, const float* __restrict__ b1v,
                                                    const float* __restrict__ W12, const float* __restrict__ c12,
                                                    const int* __restrict__ perm, float* __restrict__ AB){
  __shared__ float sm[256];
  int col = blockIdx.x;        // 0..127
  int k = col & 63;
  bool isA = col < 64;
  int tm = threadIdx.x;        // 0..255
  float a0 = a1[tm], b0 = b1v[tm];
  float w0 = W12[tm*64 + k];
  bool act0 = (a0 < 0.f) || (a0 == 0.f && b0 > 0.f);
  float coeff0 = isA ? a0 : b0;
  sm[tm] = act0 ? coeff0*w0 : 0.f;
  __syncthreads();
  for (int off2 = 128; off2 > 0; off2 >>= 1){
    if (tm < off2) sm[tm] += sm[tm + off2];
    __syncthreads();
  }
  float base = sm[0] + (isA ? 0.f : c12[k]);
  __syncthreads();
  int g = perm[tm];
  float ag = a1[g], bg = b1v[g];
  float wg = W12[g*64 + k];
  float cg = isA ? ag : bg;
  float delta = (ag > 0.f) ? cg*wg : ((ag < 0.f) ? -cg*wg : 0.f);
  sm[tm] = delta;
  __syncthreads();
  for (int off = 1; off < 256; off <<= 1){
    float v = (tm >= off) ? sm[tm-off] : 0.f;
    __syncthreads();
    sm[tm] += v;
    __syncthreads();
  }
  AB[(tm+1)*128 + col] = base + sm[tm];
  if (tm == 0) AB[col] = base;
}

__global__ void init_gpos(int* __restrict__ gpos, int nb){
  int i = blockIdx.x*256 + threadIdx.x;
  if (i < nb) gpos[i] = i * SLACK;
}

// ---------- pass 1: bin edges by dst bucket (block-local counting sort) ----------
__global__ __launch_bounds__(512) void bin_edges(const int* __restrict__ ei, int* __restrict__ gpos,
                                                 uint32_t* __restrict__ binned, int E, int nb){
  __shared__ int hist[512];
  __shared__ int sc[512];
  __shared__ int cur[512];
  __shared__ int gbase[512];
  __shared__ uint32_t staged[TILE];
  __shared__ uint16_t bof[TILE];
  int t = threadIdx.x;
  int base = blockIdx.x * TILE;
  hist[t] = 0;
  __syncthreads();
  #pragma unroll
  for (int k = 0; k < TILE/512; ++k){
    int e = base + t + k*512;
    if (e < E) atomicAdd(&hist[ei[E + e] >> BSH], 1);
  }
  __syncthreads();
  int mycnt = hist[t];
  sc[t] = mycnt;
  __syncthreads();
  for (int off = 1; off < 512; off <<= 1){
    int v = (t >= off) ? sc[t-off] : 0;
    __syncthreads();
    sc[t] += v;
    __syncthreads();
  }
  int excl = sc[t] - mycnt;
  hist[t] = excl;
  cur[t]  = excl;
  if (t < nb && mycnt > 0) gbase[t] = atomicAdd(&gpos[t], mycnt);
  __syncthreads();
  #pragma unroll
  for (int k = 0; k < TILE/512; ++k){
    int e = base + t + k*512;
    if (e < E){
      int d = ei[E + e];
      int s = ei[e];
      int b = d >> BSH;
      int slot = atomicAdd(&cur[b], 1);
      staged[slot] = ((uint32_t)(d & (BW-1)) << 17) | (uint32_t)s;
      bof[slot] = (uint16_t)b;
    }
  }
  __syncthreads();
  int tileCount = min(TILE, E - base);
  for (int i = t; i < tileCount; i += 512){
    int b = bof[i];
    binned[gbase[b] + (i - hist[b])] = staged[i];
  }
}

// ---------- exclusive scan of bucket counts -> global col base ----------
__global__ __launch_bounds__(512) void scan_buckets(const int* __restrict__ gpos, int* __restrict__ bucket_base,
                                                    int* __restrict__ rowstart, int nb, int n, int E){
  __shared__ int sm[512];
  int t = threadIdx.x;
  int c = (t < nb) ? (gpos[t] - t*SLACK) : 0;
  sm[t] = c; __syncthreads();
  for (int off = 1; off < 512; off <<= 1){
    int v = (t >= off) ? sm[t-off] : 0;
    __syncthreads();
    sm[t] += v;
    __syncthreads();
  }
  if (t < nb) bucket_base[t] = sm[t] - c;
  if (t == 0) rowstart[n] = E;
}

// ---------- pass 2: within-bucket sort by dst -> CSR (col + rowstart) ----------
__global__ __launch_bounds__(512) void sort_bucket(const uint32_t* __restrict__ binned, const int* __restrict__ gpos,
                                                   const int* __restrict__ bucket_base, int* __restrict__ rowstart,
                                                   int* __restrict__ col, int n){
  __shared__ int hist[BW];
  __shared__ int sc[BW];
  __shared__ int cur[BW];
  int b = blockIdx.x, t = threadIdx.x;
  int cnt = gpos[b] - b*SLACK;
  const uint32_t* src = binned + (size_t)b*SLACK;
  if (t < BW) hist[t] = 0;
  __syncthreads();
  for (int i = t; i < cnt; i += 512) atomicAdd(&hist[src[i] >> 17], 1);
  __syncthreads();
  if (t < BW) sc[t] = hist[t];
  __syncthreads();
  for (int off = 1; off < BW; off <<= 1){
    int v = (t < BW && t >= off) ? sc[t-off] : 0;
    __syncthreads();
    if (t < BW) sc[t] += v;
    __syncthreads();
  }
  int base = bucket_base[b];
  if (t < BW){
    int e = sc[t] - hist[t];
    cur[t] = base + e;
    int node = (b << BSH) + t;
    if (node < n) rowstart[node] = base + e;
  }
  __syncthreads();
  for (int i = t; i < cnt; i += 512){
    uint32_t e = src[i];
    int p = atomicAdd(&cur[e >> 17], 1);
    col[p] = (int)(e & 0x1FFFFu);
  }
}

// ---------- GIN1 via piecewise-linear table: 4 lanes/node, writes t bf16 ----------
__global__ __launch_bounds__(256) void gin1_pwl(const float* __restrict__ x,
    const int* __restrict__ rowstart, const int* __restrict__ col,
    const float* __restrict__ sorted_p, const float* __restrict__ AB,
    unsigned short* __restrict__ t, int n){
  __shared__ float sp[256];
  sp[threadIdx.x] = sorted_p[threadIdx.x];
  __syncthreads();
  int tid = blockIdx.x*256 + threadIdx.x;
  int node = tid >> 2, sub = tid & 3;       // 4 lanes per node, lane=16 channels
  if (node >= n) return;
  int beg = rowstart[node], end = rowstart[node+1];
  float s = 0.f;
  for (int j = beg + sub; j < end; j += 4) s += x[col[j]];
  s += __shfl_xor(s, 1);
  s += __shfl_xor(s, 2);
  s += x[node];
  int lo = 0, hi = 256;
  while (lo < hi){
    int mid = (lo + hi) >> 1;
    if (sp[mid] <= s) lo = mid + 1; else hi = mid;
  }
  const float* ab = AB + lo*128 + sub*16;
  const float4* Ap = reinterpret_cast<const float4*>(ab);
  const float4* Bp = reinterpret_cast<const float4*>(ab + 64);
  uint4 o0, o1;
  {
    float4 A0 = Ap[0], A1 = Ap[1], B0 = Bp[0], B1 = Bp[1];
    o0.x = bf16bits(fmaf(A0.x,s,B0.x)) | (bf16bits(fmaf(A0.y,s,B0.y))<<16);
    o0.y = bf16bits(fmaf(A0.z,s,B0.z)) | (bf16bits(fmaf(A0.w,s,B0.w))<<16);
    o0.z = bf16bits(fmaf(A1.x,s,B1.x)) | (bf16bits(fmaf(A1.y,s,B1.y))<<16);
    o0.w = bf16bits(fmaf(A1.z,s,B1.z)) | (bf16bits(fmaf(A1.w,s,B1.w))<<16);
  }
  {
    float4 A2v = Ap[2], A3 = Ap[3], B2v = Bp[2], B3 = Bp[3];
    o1.x = bf16bits(fmaf(A2v.x,s,B2v.x)) | (bf16bits(fmaf(A2v.y,s,B2v.y))<<16);
    o1.y = bf16bits(fmaf(A2v.z,s,B2v.z)) | (bf16bits(fmaf(A2v.w,s,B2v.w))<<16);
    o1.z = bf16bits(fmaf(A3.x,s,B3.x)) | (bf16bits(fmaf(A3.y,s,B3.y))<<16);
    o1.w = bf16bits(fmaf(A3.z,s,B3.z)) | (bf16bits(fmaf(A3.w,s,B3.w))<<16);
  }
  uint4* dst = reinterpret_cast<uint4*>(t + (size_t)node*64 + sub*16);
  dst[0] = o0;
  dst[1] = o1;
}

// ---------- GIN2 aggregation: 8 nodes/wave, 8 lanes/node, register accum ----------
// LEAN on purpose (VGPR 24, occ 60%, 2.5 TB/s): do NOT fuse head here (round-11 lesson).
__global__ __launch_bounds__(256) void agg8(const int* __restrict__ rowstart, const int* __restrict__ col,
                                            const unsigned short* __restrict__ t,
                                            const float* __restrict__ A2, const float* __restrict__ B2,
                                            unsigned short* __restrict__ r2, int n){
  int tid = blockIdx.x*256 + threadIdx.x;
  int lane = threadIdx.x & 63;
  int node = ((tid >> 6) << 3) + (lane >> 3);
  int slot = lane & 7;                      // 8-channel slot within the row
  bool valid = node < n;
  int beg = valid ? rowstart[node] : 0;
  int end = valid ? rowstart[node+1] : 0;
  float acc[8];
  {  // self row
    const uint4* trow = reinterpret_cast<const uint4*>(t + ((size_t)(valid ? node : 0))*64 + slot*8);
    uint4 v = *trow;
    acc[0]=bf16tof(v.x&0xFFFFu); acc[1]=bf16tof(v.x>>16);
    acc[2]=bf16tof(v.y&0xFFFFu); acc[3]=bf16tof(v.y>>16);
    acc[4]=bf16tof(v.z&0xFFFFu); acc[5]=bf16tof(v.z>>16);
    acc[6]=bf16tof(v.w&0xFFFFu); acc[7]=bf16tof(v.w>>16);
    if (!valid){
      #pragma unroll
      for (int q = 0; q < 8; ++q) acc[q] = 0.f;
    }
  }
  for (int j = beg; __any(j < end); j += 2){
    bool a0 = j < end, a1 = j + 1 < end;
    int s0 = a0 ? col[j] : 0;
    int s1 = a1 ? col[j+1] : 0;
    uint4 w0, w1;
    if (a0) w0 = *reinterpret_cast<const uint4*>(t + (size_t)s0*64 + slot*8);
    if (a1) w1 = *reinterpret_cast<const uint4*>(t + (size_t)s1*64 + slot*8);
    if (a0) acc8(acc, w0);
    if (a1) acc8(acc, w1);
  }
  if (valid){
    const float4* Ap = reinterpret_cast<const float4*>(A2 + slot*8);
    const float4* Bp = reinterpret_cast<const float4*>(B2 + slot*8);
    float4 A0 = Ap[0], A1 = Ap[1], B0 = Bp[0], B1 = Bp[1];
    float Av[8] = {A0.x,A0.y,A0.z,A0.w,A1.x,A1.y,A1.z,A1.w};
    float Bv[8] = {B0.x,B0.y,B0.z,B0.w,B1.x,B1.y,B1.z,B1.w};
    float r[8];
    #pragma unroll
    for (int q = 0; q < 8; ++q) r[q] = fmaxf(fmaf(acc[q], Av[q], Bv[q]), 0.f);
    uint4 o;
    o.x = bf16bits(r[0]) | (bf16bits(r[1])<<16);
    o.y = bf16bits(r[2]) | (bf16bits(r[3])<<16);
    o.z = bf16bits(r[4]) | (bf16bits(r[5])<<16);
    o.w = bf16bits(r[6]) | (bf16bits(r[7])<<16);
    *reinterpret_cast<uint4*>(r2 + (size_t)node*64 + slot*8) = o;
  }
}

// ---------- folded head: z = r@Wbl + cbl ; relu ; @wl2 + bl2 ; log_softmax ----------
// 1 thread/node; Wbl rows are wave-uniform -> s_load (round-12 lesson: keep
// weight addresses uniform, NOT lane-dependent).
__global__ __launch_bounds__(256) void head_fold(const unsigned short* __restrict__ r2,
    const float* __restrict__ Wbl, const float* __restrict__ cbl,
    const float* __restrict__ wl2, const float* __restrict__ bl2,
    float* __restrict__ out, int n){
  int i = blockIdx.x*256 + threadIdx.x;
  if (i >= n) return;
  float z[16];
  #pragma unroll
  for (int j = 0; j < 16; ++j) z[j] = cbl[j];
  const uint4* rr = reinterpret_cast<const uint4*>(r2 + (size_t)i*64);
  for (int q = 0; q < 8; ++q){      // 8 bf16 per uint4
    uint4 rv = rr[q];
    uint32_t wv[4] = {rv.x, rv.y, rv.z, rv.w};
    #pragma unroll
    for (int e2 = 0; e2 < 4; ++e2){
      float rlo = bf16tof(wv[e2] & 0xFFFFu);
      float rhi = bf16tof(wv[e2] >> 16);
      const float* wr0 = Wbl + (q*8 + e2*2)*16;   // wave-uniform -> s_load
      #pragma unroll
      for (int j = 0; j < 16; ++j) z[j] = fmaf(rlo, wr0[j], z[j]);
      const float* wr1 = wr0 + 16;
      #pragma unroll
      for (int j = 0; j < 16; ++j) z[j] = fmaf(rhi, wr1[j], z[j]);
    }
  }
  float lg[6];
  #pragma unroll
  for (int l = 0; l < 6; ++l) lg[l] = bl2[l];
  #pragma unroll
  for (int j = 0; j < 16; ++j){
    float zj = fmaxf(z[j], 0.f);
    const float* wr = wl2 + j*6;
    #pragma unroll
    for (int l = 0; l < 6; ++l) lg[l] = fmaf(zj, wr[l], lg[l]);
  }
  float mx = lg[0];
  #pragma unroll
  for (int l = 1; l < 6; ++l) mx = fmaxf(mx, lg[l]);
  float sum = 0.f;
  #pragma unroll
  for (int l = 0; l < 6; ++l) sum += expf(lg[l] - mx);
  float lse = mx + logf(sum);
  float* op = out + (size_t)i*6;
  #pragma unroll
  for (int l = 0; l < 6; ++l) op[l] = lg[l] - lse;
}

extern "C" void kernel_launch(void* const* d_in, const int* in_sizes, int n_in,
                              void* d_out, int out_size, void* d_ws, size_t ws_size,
                              hipStream_t stream){
  const float* x   = (const float*)d_in[0];
  const int*   ei  = (const int*)d_in[1];
  const float* w1a = (const float*)d_in[2];
  const float* b1a = (const float*)d_in[3];
  const float* g1  = (const float*)d_in[4];
  const float* be1 = (const float*)d_in[5];
  const float* m1  = (const float*)d_in[6];
  const float* v1  = (const float*)d_in[7];
  const float* w1b = (const float*)d_in[8];
  const float* b1b = (const float*)d_in[9];
  const float* w2a = (const float*)d_in[10];
  const float* b2a = (const float*)d_in[11];
  const float* g2  = (const float*)d_in[12];
  const float* be2 = (const float*)d_in[13];
  const float* m2  = (const float*)d_in[14];
  const float* v2  = (const float*)d_in[15];
  const float* w2b = (const float*)d_in[16];
  const float* b2b = (const float*)d_in[17];
  const float* wl1 = (const float*)d_in[18];
  const float* bl1 = (const float*)d_in[19];
  const float* wl2 = (const float*)d_in[20];
  const float* bl2 = (const float*)d_in[21];
  float* out = (float*)d_out;
  int n = in_sizes[0];        // N
  int E = in_sizes[1] / 2;    // edges
  int nb = (n + BW - 1) >> BSH;

  char* ws = (char*)d_ws;
  size_t off = 0;
  auto carve = [&](size_t bytes)->char*{ char* p = ws + off; off += (bytes + 255) & ~(size_t)255; return p; };
  float* a1   = (float*)carve(256*4);
  float* b1v  = (float*)carve(256*4);
  float* c12  = (float*)carve(64*4);
  float* A2   = (float*)carve(64*4);
  float* B2   = (float*)carve(64*4);
  float* W12  = (float*)carve(16384*4);
  float* Wbl  = (float*)carve(1024*4);
  float* cbl  = (float*)carve(16*4);
  float* sorted_p = (float*)carve(256*4);
  int*   perm = (int*)carve(256*4);
  float* AB   = (float*)carve(257*128*4);
  int* gpos   = (int*)carve((size_t)nb*4);
  int* bucket_base = (int*)carve((size_t)nb*4);
  int* rowstart = (int*)carve((size_t)(n+1)*4);
  int* col    = (int*)carve((size_t)E*4);
  uint32_t* binned = (uint32_t*)carve((size_t)nb*SLACK*4);
  unsigned short* t  = (unsigned short*)binned;   // alias: binned dead after sort_bucket
  unsigned short* r2 = (unsigned short*)carve((size_t)n*64*2);

  int nblk = (n + 255) / 256;
  prep_small<<<1, 256, 0, stream>>>(w1a,b1a,g1,be1,m1,v1,b1b,w2a,b2a,g2,be2,m2,v2,
                                    a1,b1v,c12,A2,B2,sorted_p,perm);
  prep_w12<<<64, 256, 0, stream>>>(w1b, w2a, W12);
  prep_head_fold<<<4, 256, 0, stream>>>(w2b, b2b, wl1, bl1, Wbl, cbl);
  build_ab_par<<<128, 256, 0, stream>>>(a1, b1v, W12, c12, perm, AB);
  init_gpos<<<(nb + 255)/256, 256, 0, stream>>>(gpos, nb);
  bin_edges<<<(E + TILE - 1)/TILE, 512, 0, stream>>>(ei, gpos, binned, E, nb);
  scan_buckets<<<1, 512, 0, stream>>>(gpos, bucket_base, rowstart, nb, n, E);
  sort_bucket<<<nb, 512, 0, stream>>>(binned, gpos, bucket_base, rowstart, col, n);
  gin1_pwl<<<((size_t)n*4 + 255)/256, 256, 0, stream>>>(x, rowstart, col, sorted_p, AB, t, n);
  agg8<<<(n + 31)/32, 256, 0, stream>>>(rowstart, col, t, A2, B2, r2, n);
  head_fold<<<nblk, 256, 0, stream>>>(r2, Wbl, cbl, wl2, bl2, out, n);
}